// Round 7
// baseline (53.119 us; speedup 1.0000x reference)
//
#include <hip/hip_runtime.h>

// Per-channel piecewise-linear calibration, real part only (out_size == N).
// x_real: [B=4, C=128, H=256, W=256] f32; xp,yp: [C=128, K=101] f32, xp sorted.
//
// One-LDS-round-trip eval: per-bin SoA (xhi, a, b) -> 3 independent b32 reads,
// fast-path fma for ~94% of lanes; rare slow path walks segments from jlo[bin].

#define K_BP    101
#define K_PAD   128
#define NCH     128
#define HW      65536
#define BLK     256
#define NBINS   1024
#define BPT     (NBINS / BLK)          // 4 bins built per thread
#define CPB     4096                   // elements per block (16 blocks/plane)
#define ITERS   (CPB / (BLK * 4))      // 4 iters, one f32x4 per thread per iter
#define MARGIN  1e-5f                  // > worst-case bin-map rounding (~1e-6)

typedef float f32x4 __attribute__((ext_vector_type(4)));

__global__ __launch_bounds__(BLK) void pwl_real_kernel(
    const float* __restrict__ xr,
    const float* __restrict__ xp, const float* __restrict__ yp,
    float* __restrict__ out)
{
    __shared__ float         xp_s[K_PAD];      // +inf padded breakpoints
    __shared__ float2        ab_s[K_BP - 1];   // per-SEGMENT (a,b) for slow path
    __shared__ float         xhi_s[NBINS];     // per-bin: end of lower-bound segment
    __shared__ float         a_s[NBINS];       // per-bin: segment a
    __shared__ float         b_s[NBINS];       // per-bin: segment b
    __shared__ unsigned char jlo_s[NBINS];     // per-bin: lower-bound segment idx

    const int t     = threadIdx.x;
    const int bid   = blockIdx.x;
    const int plane = bid >> 4;                // 16 blocks per (b,c) plane
    const int chunk = bid & 15;
    const int c     = plane & (NCH - 1);
    const unsigned int base = (unsigned int)plane * HW + (unsigned int)chunk * CPB;

    if (t < K_PAD) {
        xp_s[t] = (t < K_BP) ? xp[c * K_BP + t] : __builtin_inff();
    }
    __syncthreads();

    // Per-segment a = (y1-y0)/(x1-x0) (ref arithmetic), b = y0 - x0*a.
    if (t < K_BP - 1) {
        float x0 = xp_s[t], x1 = xp_s[t + 1];
        float y0 = yp[c * K_BP + t], y1 = yp[c * K_BP + t + 1];
        float a  = (y1 - y0) / (x1 - x0);
        ab_s[t]  = make_float2(a, fmaf(-x0, a, y0));
    }

    const float xmin = xp_s[0];
    const float xmax = xp_s[K_BP - 1];
    const float w    = (xmax - xmin) * (1.0f / NBINS);
    const float invw = (float)NBINS / (xmax - xmin);
    __syncthreads();                            // ab_s ready (read during build)

    // Build per-bin tables. Thread t owns bins [4t, 4t+4).
    {
        const int b0 = t * BPT;
        float v = fmaf((float)b0, w, xmin) - MARGIN;
        int j = 0;
        #pragma unroll
        for (int step = 64; step >= 1; step >>= 1) {
            j += (xp_s[j + step - 1] <= v) ? step : 0;
        }
        j -= 1;
        j = j < 0 ? 0 : j;
        j = j > (K_BP - 2) ? (K_BP - 2) : j;
        #pragma unroll
        for (int i = 0; i < BPT; ++i) {
            if (i > 0) {
                float vi = fmaf((float)(b0 + i), w, xmin) - MARGIN;
                while (j < (K_BP - 2) && xp_s[j + 1] <= vi) ++j;
            }
            float2 ab = ab_s[j];
            xhi_s[b0 + i] = (j == K_BP - 2) ? __builtin_inff() : xp_s[j + 1];
            a_s[b0 + i]   = ab.x;
            b_s[b0 + i]   = ab.y;
            jlo_s[b0 + i] = (unsigned char)j;
        }
    }
    __syncthreads();

    #pragma unroll
    for (int it = 0; it < ITERS; ++it) {
        const unsigned int g = base + ((unsigned int)it * BLK + t) * 4;
        f32x4 v = *reinterpret_cast<const f32x4*>(xr + g);
        f32x4 o;
        #pragma unroll
        for (int e = 0; e < 4; ++e) {
            float x = v[e];
            int bin = (int)((x - xmin) * invw);
            bin = bin < 0 ? 0 : bin;
            bin = bin > (NBINS - 1) ? (NBINS - 1) : bin;
            float xhi = xhi_s[bin];              // 3 independent b32 reads:
            float a   = a_s[bin];                // one LDS round-trip total
            float b   = b_s[bin];
            if (x >= xhi) {                      // rare: bin straddles breakpoint(s)
                int j = (int)jlo_s[bin];
                while (j < (K_BP - 2) && x >= xp_s[j + 1]) ++j;
                float2 ab = ab_s[j];
                a = ab.x; b = ab.y;
            }
            o[e] = fmaf(x, a, b);
        }
        *reinterpret_cast<f32x4*>(out + g) = o;
    }
}

extern "C" void kernel_launch(void* const* d_in, const int* in_sizes, int n_in,
                              void* d_out, int out_size, void* d_ws, size_t ws_size,
                              hipStream_t stream) {
    const float* xr = (const float*)d_in[0];
    const float* xp = (const float*)d_in[2];
    const float* yp = (const float*)d_in[3];
    float* out = (float*)d_out;

    const long long N = (long long)in_sizes[0];   // 33,554,432
    const int blocks = (int)(N / CPB);            // 8192
    pwl_real_kernel<<<dim3(blocks), dim3(BLK), 0, stream>>>(xr, xp, yp, out);
}

// Round 8
// 48.804 us; speedup vs baseline: 1.0884x; 1.0884x over previous
//
#include <hip/hip_runtime.h>

// Per-channel piecewise-linear calibration, real part only (out_size == N).
// x_real: [B=4, C=128, H=256, W=256] f32; xp,yp: [C=128, K=101] f32, xp sorted.
//
// Branchless depth-2 eval:
//   c8  = #(register pivots xp[8m] <= x)          -- pure VALU, no LDS
//   cnt = 8*c8 + #(xp_s[8*c8 .. 8*c8+7] <= x)     -- one aligned window read
//   j   = clamp(cnt-1, 0, 99); y = fma(x, a_j, b_j)
// Exact searchsorted(side='right') for all x (sorted xp, +inf pad).

#define K_BP    101
#define K_PAD   128
#define NCH     128
#define HW      65536
#define BLK     256
#define CPB     4096                   // elements per block (16 blocks/plane)
#define ITERS   (CPB / (BLK * 4))      // 4 iters, one f32x4 per thread per iter
#define NPIV    12                     // pivots xp[8], xp[16], ..., xp[96]

typedef float f32x4 __attribute__((ext_vector_type(4)));

__global__ __launch_bounds__(BLK) void pwl_real_kernel(
    const float* __restrict__ xr,
    const float* __restrict__ xp, const float* __restrict__ yp,
    float* __restrict__ out)
{
    __shared__ __align__(16) float  xp_s[K_PAD];     // +inf padded breakpoints
    __shared__ __align__(16) float2 ab_s[K_BP - 1];  // per-segment (a, b)

    const int t     = threadIdx.x;
    const int bid   = blockIdx.x;
    const int plane = bid >> 4;                // 16 blocks per (b,c) plane
    const int chunk = bid & 15;
    const int c     = plane & (NCH - 1);
    const unsigned int base = (unsigned int)plane * HW + (unsigned int)chunk * CPB;

    if (t < K_PAD) {
        xp_s[t] = (t < K_BP) ? xp[c * K_BP + t] : __builtin_inff();
    }
    __syncthreads();

    // Per-segment a = (y1-y0)/(x1-x0) (ref arithmetic), b = y0 - x0*a.
    if (t < K_BP - 1) {
        float x0 = xp_s[t], x1 = xp_s[t + 1];
        float y0 = yp[c * K_BP + t], y1 = yp[c * K_BP + t + 1];
        float a  = (y1 - y0) / (x1 - x0);
        ab_s[t]  = make_float2(a, fmaf(-x0, a, y0));
    }

    // Block-uniform pivots -> registers (broadcast LDS reads, once).
    float piv[NPIV];
    #pragma unroll
    for (int m = 0; m < NPIV; ++m) piv[m] = xp_s[8 * (m + 1)];
    __syncthreads();

    #pragma unroll
    for (int it = 0; it < ITERS; ++it) {
        const unsigned int g = base + ((unsigned int)it * BLK + t) * 4;
        f32x4 v = *reinterpret_cast<const f32x4*>(xr + g);
        f32x4 o;
        #pragma unroll
        for (int e = 0; e < 4; ++e) {
            float x = v[e];
            // Coarse count: pure VALU, 12 compare-adds, no LDS, no indexing.
            int c8 = 0;
            #pragma unroll
            for (int m = 0; m < NPIV; ++m) c8 += (x >= piv[m]) ? 1 : 0;
            const int wbase = 8 * c8;          // 0..96, 32B-aligned window
            // One round-trip: 8-float window (2 parallel b128 / 4 b64).
            const f32x4 w0 = *reinterpret_cast<const f32x4*>(xp_s + wbase);
            const f32x4 w1 = *reinterpret_cast<const f32x4*>(xp_s + wbase + 4);
            int cnt = wbase;
            cnt += (x >= w0.x) ? 1 : 0;  cnt += (x >= w0.y) ? 1 : 0;
            cnt += (x >= w0.z) ? 1 : 0;  cnt += (x >= w0.w) ? 1 : 0;
            cnt += (x >= w1.x) ? 1 : 0;  cnt += (x >= w1.y) ? 1 : 0;
            cnt += (x >= w1.z) ? 1 : 0;  cnt += (x >= w1.w) ? 1 : 0;
            int j = cnt - 1;
            j = j < 0 ? 0 : j;
            j = j > (K_BP - 2) ? (K_BP - 2) : j;   // clamp -> extrapolation
            float2 ab = ab_s[j];                   // second round-trip
            o[e] = fmaf(x, ab.x, ab.y);
        }
        *reinterpret_cast<f32x4*>(out + g) = o;
    }
}

extern "C" void kernel_launch(void* const* d_in, const int* in_sizes, int n_in,
                              void* d_out, int out_size, void* d_ws, size_t ws_size,
                              hipStream_t stream) {
    const float* xr = (const float*)d_in[0];
    const float* xp = (const float*)d_in[2];
    const float* yp = (const float*)d_in[3];
    float* out = (float*)d_out;

    const long long N = (long long)in_sizes[0];   // 33,554,432
    const int blocks = (int)(N / CPB);            // 8192
    pwl_real_kernel<<<dim3(blocks), dim3(BLK), 0, stream>>>(xr, xp, yp, out);
}